// Round 1
// 486.109 us; speedup vs baseline: 1.0783x; 1.0783x over previous
//
#include <hip/hip_runtime.h>
#include <math.h>

// Batched Kalman filter step: B=131072, STATE=16, OBS=8, fp32.
// v2: single-wave blocks (64 thr = 4 batches), LDS cut 1000->616 dwords/batch
// (16 blocks/CU vs 5), all LDS broadcast reads vectorized to ds_read_b128.
// Buffer overlays rely on in-wave lockstep (DS ops execute in program order
// within a wave); __syncthreads() compiles to a fence only (single-wave WG).
//
// Per-batch LDS layout (dwords), stride 616 (== 8 mod 32 so the 4 groups of
// a wave broadcast from disjoint bank quads):
//   Mb @   0 : 256  16x16 stride 16  cov -> tmp^T -> new_cov -> FP^T
//   Hb @ 256 : 128  8x16  stride 16  (b128-readable)
//   Rb @ 384 :  64  8x8   stride 8
//   Xb @ 448 : 128  PHt(16x8,s8) -> S(8x8,s8) -> K^T(8x16,s16)
//   meanv @576: 16 ; rn @592: 16 (resid(8) -> new_mean(16)) ; pad -> 616
// Symmetry tricks: new_cov = p1·tmp^T (tmp = p1·cov), pred_cov = F·FP^T + Q
// (FP = F·new_cov) — removes the p1T / F^T buffers of v1 entirely.

#define NB 131072
#define BPB 4
#define THREADS 64
#define LDS_PER 616

#define ROW_FMA16(acc, s, base) do {                                        \
    const float4* _r = (const float4*)(base);                               \
    float4 _c0=_r[0], _c1=_r[1], _c2=_r[2], _c3=_r[3];                      \
    acc[0]+=(s)*_c0.x; acc[1]+=(s)*_c0.y; acc[2]+=(s)*_c0.z; acc[3]+=(s)*_c0.w; \
    acc[4]+=(s)*_c1.x; acc[5]+=(s)*_c1.y; acc[6]+=(s)*_c1.z; acc[7]+=(s)*_c1.w; \
    acc[8]+=(s)*_c2.x; acc[9]+=(s)*_c2.y; acc[10]+=(s)*_c2.z; acc[11]+=(s)*_c2.w; \
    acc[12]+=(s)*_c3.x; acc[13]+=(s)*_c3.y; acc[14]+=(s)*_c3.z; acc[15]+=(s)*_c3.w; \
} while (0)

#define ROW_FMA8(acc, s, base) do {                                         \
    const float4* _r = (const float4*)(base);                               \
    float4 _c0=_r[0], _c1=_r[1];                                            \
    acc[0]+=(s)*_c0.x; acc[1]+=(s)*_c0.y; acc[2]+=(s)*_c0.z; acc[3]+=(s)*_c0.w; \
    acc[4]+=(s)*_c1.x; acc[5]+=(s)*_c1.y; acc[6]+=(s)*_c1.z; acc[7]+=(s)*_c1.w; \
} while (0)

__global__ void __launch_bounds__(THREADS, 4)
kalman_step_kernel(const float* __restrict__ input, const float* __restrict__ mean,
                   const float* __restrict__ cov, const float* __restrict__ H,
                   const float* __restrict__ R, const float* __restrict__ F,
                   const float* __restrict__ Q,
                   float* __restrict__ out_mean, float* __restrict__ out_cov)
{
    __shared__ __align__(16) float lds[BPB * LDS_PER];

    const int tid = threadIdx.x;
    const int g = tid >> 4;        // batch slot (0..3)
    const int t = tid & 15;        // state row
    const long b = (long)blockIdx.x * BPB + g;

    float* Lb    = lds + g * LDS_PER;
    float* Mb    = Lb;
    float* Hb    = Lb + 256;
    float* Rb    = Lb + 384;
    float* Xb    = Lb + 448;
    float* meanv = Lb + 576;
    float* rn    = Lb + 592;

    // ---------------- Phase 1: global loads (cov, H, R, mean, input) ----------------
    float covrow[16];
    {
        const float4* C4 = (const float4*)(cov + b * 256 + t * 16);
        float4 c0 = C4[0], c1 = C4[1], c2 = C4[2], c3 = C4[3];
        covrow[0]=c0.x; covrow[1]=c0.y; covrow[2]=c0.z; covrow[3]=c0.w;
        covrow[4]=c1.x; covrow[5]=c1.y; covrow[6]=c1.z; covrow[7]=c1.w;
        covrow[8]=c2.x; covrow[9]=c2.y; covrow[10]=c2.z; covrow[11]=c2.w;
        covrow[12]=c3.x; covrow[13]=c3.y; covrow[14]=c3.z; covrow[15]=c3.w;
        float4* md = (float4*)(Mb + t * 16);
        md[0]=c0; md[1]=c1; md[2]=c2; md[3]=c3;
    }
    const float m = mean[b * 16 + t];
    meanv[t] = m;

    float hreg[16];
    float rreg[8];
    float inp = 0.0f;
    if (t < 8) {
        inp = input[b * 8 + t];
        const float4* H4 = (const float4*)(H + b * 128 + t * 16);
        float4 h0 = H4[0], h1 = H4[1], h2 = H4[2], h3 = H4[3];
        hreg[0]=h0.x; hreg[1]=h0.y; hreg[2]=h0.z; hreg[3]=h0.w;
        hreg[4]=h1.x; hreg[5]=h1.y; hreg[6]=h1.z; hreg[7]=h1.w;
        hreg[8]=h2.x; hreg[9]=h2.y; hreg[10]=h2.z; hreg[11]=h2.w;
        hreg[12]=h3.x; hreg[13]=h3.y; hreg[14]=h3.z; hreg[15]=h3.w;
        float4* hd = (float4*)(Hb + t * 16);
        hd[0]=h0; hd[1]=h1; hd[2]=h2; hd[3]=h3;
        const float4* R4 = (const float4*)(R + b * 64 + t * 8);
        float4 r0 = R4[0], r1 = R4[1];
        rreg[0]=r0.x; rreg[1]=r0.y; rreg[2]=r0.z; rreg[3]=r0.w;
        rreg[4]=r1.x; rreg[5]=r1.y; rreg[6]=r1.z; rreg[7]=r1.w;
        float4* rd = (float4*)(Rb + t * 8);
        rd[0]=r0; rd[1]=r1;
    }
    __syncthreads();

    // ---------------- Phase 2: PHt = cov @ H^T (row t); resid ----------------
    float pht[8];
    #pragma unroll
    for (int o = 0; o < 8; ++o) {
        const float4* hr = (const float4*)(Hb + o * 16);
        float4 h0 = hr[0], h1 = hr[1], h2 = hr[2], h3 = hr[3];
        float acc;
        acc  = covrow[0]*h0.x + covrow[1]*h0.y + covrow[2]*h0.z + covrow[3]*h0.w;
        acc += covrow[4]*h1.x + covrow[5]*h1.y + covrow[6]*h1.z + covrow[7]*h1.w;
        acc += covrow[8]*h2.x + covrow[9]*h2.y + covrow[10]*h2.z + covrow[11]*h2.w;
        acc += covrow[12]*h3.x + covrow[13]*h3.y + covrow[14]*h3.z + covrow[15]*h3.w;
        pht[o] = acc;
    }
    {
        float4* pd = (float4*)(Xb + t * 8);
        pd[0] = make_float4(pht[0], pht[1], pht[2], pht[3]);
        pd[1] = make_float4(pht[4], pht[5], pht[6], pht[7]);
    }
    if (t < 8) {
        const float4* mv = (const float4*)meanv;
        float4 m0 = mv[0], m1 = mv[1], m2 = mv[2], m3 = mv[3];
        float acc = inp;
        acc -= hreg[0]*m0.x + hreg[1]*m0.y + hreg[2]*m0.z + hreg[3]*m0.w;
        acc -= hreg[4]*m1.x + hreg[5]*m1.y + hreg[6]*m1.z + hreg[7]*m1.w;
        acc -= hreg[8]*m2.x + hreg[9]*m2.y + hreg[10]*m2.z + hreg[11]*m2.w;
        acc -= hreg[12]*m3.x + hreg[13]*m3.y + hreg[14]*m3.z + hreg[15]*m3.w;
        rn[t] = acc;
    }
    __syncthreads();

    // ---------------- Phase 3: S = H @ PHt + R (rows t<8); S overwrites PHt[0:7] ----------------
    if (t < 8) {
        float sreg[8];
        #pragma unroll
        for (int c = 0; c < 8; ++c) sreg[c] = rreg[c];
        #pragma unroll
        for (int s = 0; s < 16; ++s) {
            float h = hreg[s];
            ROW_FMA8(sreg, h, Xb + s * 8);
        }
        // in-wave lockstep: all PHt reads above complete before this write issues
        float4* sd = (float4*)(Xb + t * 8);
        sd[0] = make_float4(sreg[0], sreg[1], sreg[2], sreg[3]);
        sd[1] = make_float4(sreg[4], sreg[5], sreg[6], sreg[7]);
    }
    __syncthreads();

    // ---------------- Phase 4: redundant Cholesky; K row; new_mean; K^T -> Xb ----------------
    float Lm[8][8];
    #pragma unroll
    for (int i = 0; i < 8; ++i) {
        const float4* sr = (const float4*)(Xb + i * 8);
        float4 s0 = sr[0], s1 = sr[1];
        Lm[i][0]=s0.x; Lm[i][1]=s0.y; Lm[i][2]=s0.z; Lm[i][3]=s0.w;
        Lm[i][4]=s1.x; Lm[i][5]=s1.y; Lm[i][6]=s1.z; Lm[i][7]=s1.w;
    }
    float dinv[8];
    #pragma unroll
    for (int k = 0; k < 8; ++k) {
        float diag = Lm[k][k];
        #pragma unroll
        for (int j = 0; j < k; ++j) diag -= Lm[k][j] * Lm[k][j];
        float lkk = sqrtf(diag);
        float inv = 1.0f / lkk;
        dinv[k] = inv;
        #pragma unroll
        for (int i = k + 1; i < 8; ++i) {
            float v = Lm[i][k];
            #pragma unroll
            for (int j = 0; j < k; ++j) v -= Lm[i][j] * Lm[k][j];
            Lm[i][k] = v * inv;
        }
    }
    float yv[8];
    #pragma unroll
    for (int i = 0; i < 8; ++i) {
        float v = pht[i];
        #pragma unroll
        for (int j = 0; j < i; ++j) v -= Lm[i][j] * yv[j];
        yv[i] = v * dinv[i];
    }
    float Kr[8];
    #pragma unroll
    for (int i = 7; i >= 0; --i) {
        float v = yv[i];
        #pragma unroll
        for (int j = i + 1; j < 8; ++j) v -= Lm[j][i] * Kr[j];
        Kr[i] = v * dinv[i];
    }
    // new_mean (reads resid broadcast, then overwrites rn[t] — lockstep-safe)
    {
        const float4* rv = (const float4*)rn;
        float4 r0 = rv[0], r1 = rv[1];
        float nm = m;
        nm += Kr[0]*r0.x + Kr[1]*r0.y + Kr[2]*r0.z + Kr[3]*r0.w;
        nm += Kr[4]*r1.x + Kr[5]*r1.y + Kr[6]*r1.z + Kr[7]*r1.w;
        rn[t] = nm;
    }
    // K^T (8x16, stride 16) over Xb; S reads above are done (lockstep)
    #pragma unroll
    for (int o = 0; o < 8; ++o) Xb[o * 16 + t] = Kr[o];
    __syncthreads();

    // ---------------- Phase 5: p1 = I - K@H (row); KR = K@R (row); prefetch F ----------------
    const float4* F4 = (const float4*)(F + b * 256 + t * 16);
    float4 fA = F4[0], fB = F4[1], fC = F4[2], fD = F4[3];

    float p1r[16];
    #pragma unroll
    for (int j = 0; j < 16; ++j) p1r[j] = (j == t) ? 1.0f : 0.0f;
    #pragma unroll
    for (int o = 0; o < 8; ++o) {
        float nko = -Kr[o];
        ROW_FMA16(p1r, nko, Hb + o * 16);
    }
    float KRr[8];
    #pragma unroll
    for (int c = 0; c < 8; ++c) KRr[c] = 0.0f;
    #pragma unroll
    for (int o = 0; o < 8; ++o) {
        float ko = Kr[o];
        ROW_FMA8(KRr, ko, Rb + o * 8);
    }

    // ---------------- Phase 6: tmp = p1 @ cov (row); then tmp^T -> Mb ----------------
    float tmp[16];
    #pragma unroll
    for (int k = 0; k < 16; ++k) tmp[k] = 0.0f;
    #pragma unroll
    for (int j = 0; j < 16; ++j) {
        float pj = p1r[j];
        ROW_FMA16(tmp, pj, Mb + j * 16);
    }
    __syncthreads();
    #pragma unroll
    for (int k = 0; k < 16; ++k) Mb[k * 16 + t] = tmp[k];
    __syncthreads();

    // ---------------- Phase 7: new_cov row = p1 @ tmp^T + KR @ K^T ; prefetch Q ----------------
    const float4* Q4 = (const float4*)(Q + b * 256 + t * 16);
    float4 qA = Q4[0], qB = Q4[1], qC = Q4[2], qD = Q4[3];

    float nc[16];
    #pragma unroll
    for (int j = 0; j < 16; ++j) nc[j] = 0.0f;
    #pragma unroll
    for (int k = 0; k < 16; ++k) {
        float pk = p1r[k];
        ROW_FMA16(nc, pk, Mb + k * 16);
    }
    #pragma unroll
    for (int o = 0; o < 8; ++o) {
        float ko = KRr[o];
        ROW_FMA16(nc, ko, Xb + o * 16);
    }
    __syncthreads();
    {
        float4* md = (float4*)(Mb + t * 16);
        md[0] = make_float4(nc[0], nc[1], nc[2], nc[3]);
        md[1] = make_float4(nc[4], nc[5], nc[6], nc[7]);
        md[2] = make_float4(nc[8], nc[9], nc[10], nc[11]);
        md[3] = make_float4(nc[12], nc[13], nc[14], nc[15]);
    }
    __syncthreads();

    // ---------------- Phase 9: FP = F @ new_cov (row); pred_mean; FP^T -> Mb ----------------
    float freg[16];
    freg[0]=fA.x; freg[1]=fA.y; freg[2]=fA.z; freg[3]=fA.w;
    freg[4]=fB.x; freg[5]=fB.y; freg[6]=fB.z; freg[7]=fB.w;
    freg[8]=fC.x; freg[9]=fC.y; freg[10]=fC.z; freg[11]=fC.w;
    freg[12]=fD.x; freg[13]=fD.y; freg[14]=fD.z; freg[15]=fD.w;

    float fp[16];
    #pragma unroll
    for (int k = 0; k < 16; ++k) fp[k] = 0.0f;
    #pragma unroll
    for (int j = 0; j < 16; ++j) {
        float fj = freg[j];
        ROW_FMA16(fp, fj, Mb + j * 16);
    }
    float pm;
    {
        const float4* rv = (const float4*)rn;
        float4 r0 = rv[0], r1 = rv[1], r2 = rv[2], r3 = rv[3];
        pm  = freg[0]*r0.x + freg[1]*r0.y + freg[2]*r0.z + freg[3]*r0.w;
        pm += freg[4]*r1.x + freg[5]*r1.y + freg[6]*r1.z + freg[7]*r1.w;
        pm += freg[8]*r2.x + freg[9]*r2.y + freg[10]*r2.z + freg[11]*r2.w;
        pm += freg[12]*r3.x + freg[13]*r3.y + freg[14]*r3.z + freg[15]*r3.w;
    }
    __syncthreads();
    #pragma unroll
    for (int k = 0; k < 16; ++k) Mb[k * 16 + t] = fp[k];
    __syncthreads();

    // ---------------- Phase 10: pred_cov row = F @ FP^T + Q ; stores ----------------
    float pc[16];
    pc[0]=qA.x; pc[1]=qA.y; pc[2]=qA.z; pc[3]=qA.w;
    pc[4]=qB.x; pc[5]=qB.y; pc[6]=qB.z; pc[7]=qB.w;
    pc[8]=qC.x; pc[9]=qC.y; pc[10]=qC.z; pc[11]=qC.w;
    pc[12]=qD.x; pc[13]=qD.y; pc[14]=qD.z; pc[15]=qD.w;
    #pragma unroll
    for (int k = 0; k < 16; ++k) {
        float fk = freg[k];
        ROW_FMA16(pc, fk, Mb + k * 16);
    }

    out_mean[b * 16 + t] = pm;
    {
        float4* od = (float4*)(out_cov + b * 256 + t * 16);
        od[0] = make_float4(pc[0], pc[1], pc[2], pc[3]);
        od[1] = make_float4(pc[4], pc[5], pc[6], pc[7]);
        od[2] = make_float4(pc[8], pc[9], pc[10], pc[11]);
        od[3] = make_float4(pc[12], pc[13], pc[14], pc[15]);
    }
}

extern "C" void kernel_launch(void* const* d_in, const int* in_sizes, int n_in,
                              void* d_out, int out_size, void* d_ws, size_t ws_size,
                              hipStream_t stream) {
    const float* input = (const float*)d_in[0];
    const float* mean  = (const float*)d_in[1];
    const float* cov   = (const float*)d_in[2];
    const float* H     = (const float*)d_in[3];
    const float* R     = (const float*)d_in[4];
    const float* F     = (const float*)d_in[5];
    const float* Q     = (const float*)d_in[6];
    float* out = (float*)d_out;
    float* out_mean = out;
    float* out_cov  = out + (size_t)NB * 16;

    dim3 grid(NB / BPB);
    dim3 block(THREADS);
    hipLaunchKernelGGL(kalman_step_kernel, grid, block, 0, stream,
                       input, mean, cov, H, R, F, Q, out_mean, out_cov);
}